// Round 11
// baseline (2464.536 us; speedup 1.0000x reference)
//
#include <hip/hip_runtime.h>

// ---------------------------------------------------------------------------
// 2-layer LSTM (H=51) + Linear(51,1), B=1024, T=1024, fp32.
// Design (R11 = R10 step machinery, BPB=4, single generation):
//   R10 counters: VGPR=64 under a 128-unified budget -> weights parked in
//   AGPRs, v_accvgpr_read copy tax ~2x the useful issue; and 1024 blocks at
//   2 blocks/CU = 2 serial generations.
//   - 256 blocks x 512 threads, 4 batches/block -> 1 block/CU, ONE generation.
//   - waves_per_eu(2,2): unified budget 256/wave; live set ~148 fits in ARCH
//     VGPRs (weights no longer in AGPRs -> no copy tax).
//   - batches processed sequentially inside each step (min register pressure;
//     arch-resident weights make sharing unnecessary).
//   - everything else R9/R10-proven: single barrier/step, L2 one step behind
//     L1, ping-pong h buffers, transpose-reduce (lane q owns gate q), in-quad
//     DPP c/h update, v_pk asm dots, y on 16-lane spare groups one step
//     deferred (4 groups, tid 416..479).
// ---------------------------------------------------------------------------

#define H    51
#define TLEN 1024
#define BPB  4
#define NTHR 512
#define NBLK 256

typedef __attribute__((ext_vector_type(2))) float f2;
typedef __attribute__((ext_vector_type(4))) float f4;

__device__ __forceinline__ float frcp(float x) { return __builtin_amdgcn_rcpf(x); }

// packed fp32: D = A*B (+D). 64-bit VGPR-pair operands; "v" forces VGPRs.
#define PKMUL(D, A, B) asm("v_pk_mul_f32 %0, %1, %2"     : "=v"(D) : "v"(A), "v"(B))
#define PKFMA(D, A, B) asm("v_pk_fma_f32 %0, %1, %2, %0" : "+v"(D) : "v"(A), "v"(B))

// quad_perm DPP (VALU pipe): 0xB1=[1,0,3,2] xor1, 0x4E=[2,3,0,1] xor2,
// 0x00=bcast lane0, 0x55=bcast lane1.
#define DPP_GET(X, CTRL)  (__int_as_float(__builtin_amdgcn_update_dpp(       \
                              0, __float_as_int(X), CTRL, 0xF, 0xF, true)))
#define DPP_XADD(X, CTRL) ((X) + DPP_GET(X, CTRL))

__global__
__attribute__((amdgpu_flat_work_group_size(NTHR, NTHR), amdgpu_waves_per_eu(2, 2)))
void lstm2_kernel(const float* __restrict__ input,
                  const float* __restrict__ W_ih1, const float* __restrict__ W_hh1,
                  const float* __restrict__ b_ih1, const float* __restrict__ b_hh1,
                  const float* __restrict__ W_ih2, const float* __restrict__ W_hh2,
                  const float* __restrict__ b_ih2, const float* __restrict__ b_hh2,
                  const float* __restrict__ W_lin, const float* __restrict__ b_lin,
                  float* __restrict__ out)
{
    const int tid = threadIdx.x;
    const int b0  = blockIdx.x * BPB;
    const int a   = tid >> 3;        // unit 0..63 (a<51 active)
    const int c   = tid & 7;         // k-chunk 0..7 (8 floats of h)
    const int q   = c & 3;           // after reduce, this lane owns gate q
    const bool ul = (a < H);

    __shared__ __align__(16) float h1buf[BPB][2][64];   // [batch][pingpong]
    __shared__ __align__(16) float h2buf[BPB][2][64];
    __shared__ __align__(16) float sh_wl[64];           // W_lin, zero-padded

    ((float*)h1buf)[tid] = 0.0f;     // BPB*2*64 == NTHR
    ((float*)h2buf)[tid] = 0.0f;
    if (tid < 64) sh_wl[tid] = (tid < H) ? W_lin[tid] : 0.0f;

    // per-lane weights: rows g*51+a, elements [8c, 8c+8), zero-padded
    f2 w1[16], wi2[16], wh2[16];
#pragma unroll
    for (int g = 0; g < 4; ++g) {
#pragma unroll
        for (int j = 0; j < 4; ++j) {
            const int e0 = c * 8 + 2 * j, e1 = e0 + 1;
            const int r  = g * H + a;
            const bool v0 = ul && (e0 < H), v1 = ul && (e1 < H);
            w1 [g*4+j] = f2{v0 ? W_hh1[r*H+e0] : 0.f, v1 ? W_hh1[r*H+e1] : 0.f};
            wi2[g*4+j] = f2{v0 ? W_ih2[r*H+e0] : 0.f, v1 ? W_ih2[r*H+e1] : 0.f};
            wh2[g*4+j] = f2{v0 ? W_hh2[r*H+e0] : 0.f, v1 ? W_hh2[r*H+e1] : 0.f};
        }
    }
#pragma unroll
    for (int g = 0; g < 4; ++g)      // non-rematerializable (anti-R4)
        asm volatile("" : "+v"(w1[g*4+0]),  "+v"(w1[g*4+1]),  "+v"(w1[g*4+2]),  "+v"(w1[g*4+3]),
                          "+v"(wi2[g*4+0]), "+v"(wi2[g*4+1]), "+v"(wi2[g*4+2]), "+v"(wi2[g*4+3]),
                          "+v"(wh2[g*4+0]), "+v"(wh2[g*4+1]), "+v"(wh2[g*4+2]), "+v"(wh2[g*4+3]));

    const int rq = q * H + a;                      // this lane's own gate row
    const float wx  = ul ? W_ih1[rq] : 0.f;
    const float bb1 = ul ? (b_ih1[rq] + b_hh1[rq]) : 0.f;
    const float bb2 = ul ? (b_ih2[rq] + b_hh2[rq]) : 0.f;
    const float sm  = (q == 2) ? -2.0f : -1.0f;    // tanh gate as scaled sigmoid
    const float bm  = (q == 2) ? -1.0f :  0.0f;    // act = sg + bm*(1-sg)

    const int  sj    = tid - 416;                  // y lanes 416..479
    const bool ylane = ((unsigned)sj < (unsigned)(16 * BPB));
    const int  yb    = (sj >> 4) & (BPB - 1);      // batch handled by group
    const int  sjj   = sj & 15;
    const float blin = b_lin[0];

    float c1[BPB], c2[BPB];
#pragma unroll
    for (int n = 0; n < BPB; ++n) { c1[n] = 0.0f; c2[n] = 0.0f; }

    __syncthreads();                               // zeros + sh_wl visible

    for (int k = 0; k <= TLEN; ++k) {
        const int rb = (k + 1) & 1;                // holds h1(k-1), h2(k-2)
        const int wb = k & 1;
        const int kx = (k < TLEN) ? k : TLEN - 1;
        const float km = (k == 0) ? 0.0f : 1.0f;   // L2 step k-1 validity mask

        // ---- deferred y(k-2): 4 spare 16-lane groups, one per batch ----
        if (ylane && k >= 2) {
            const f4 hv = *(const f4*)&h2buf[yb][rb][sjj * 4];
            const f4 wl = *(const f4*)&sh_wl[sjj * 4];
            float yp = hv.x*wl.x + hv.y*wl.y + hv.z*wl.z + hv.w*wl.w;
            yp = DPP_XADD(yp, 0xB1);  yp = DPP_XADD(yp, 0x4E);
            yp += __shfl_xor(yp, 4);  yp += __shfl_xor(yp, 8);
            if (sjj == 0) out[(size_t)(b0 + yb) * TLEN + (k - 2)] = yp + blin;
        }

        // ---- 4 batches sequentially (weights arch-resident, reused) ----
#pragma unroll
        for (int n = 0; n < BPB; ++n) {
            const float x = input[(size_t)(b0 + n) * TLEN + kx];

            const f4* h1v = (const f4*)&h1buf[n][rb][c * 8];
            const f4* h2v = (const f4*)&h2buf[n][rb][c * 8];
            const f4 A0 = h1v[0], A1 = h1v[1];
            const f4 B0 = h2v[0], B1 = h2v[1];
            const f2 a0l = f2{A0.x, A0.y}, a0h = f2{A0.z, A0.w};
            const f2 a1l = f2{A1.x, A1.y}, a1h = f2{A1.z, A1.w};
            const f2 b0l = f2{B0.x, B0.y}, b0h = f2{B0.z, B0.w};
            const f2 b1l = f2{B1.x, B1.y}, b1h = f2{B1.z, B1.w};

            // L1 per-gate partial dots
            f2 p0, p1, p2, p3;
            PKMUL(p0, w1[0],  a0l); PKFMA(p0, w1[1],  a0h); PKFMA(p0, w1[2],  a1l); PKFMA(p0, w1[3],  a1h);
            PKMUL(p1, w1[4],  a0l); PKFMA(p1, w1[5],  a0h); PKFMA(p1, w1[6],  a1l); PKFMA(p1, w1[7],  a1h);
            PKMUL(p2, w1[8],  a0l); PKFMA(p2, w1[9],  a0h); PKFMA(p2, w1[10], a1l); PKFMA(p2, w1[11], a1h);
            PKMUL(p3, w1[12], a0l); PKFMA(p3, w1[13], a0h); PKFMA(p3, w1[14], a1l); PKFMA(p3, w1[15], a1h);
            float t0 = p0.x + p0.y, t1 = p1.x + p1.y, t2 = p2.x + p2.y, t3 = p3.x + p3.y;

            float sel1;
            {
                const float s01 = (q & 1) ? t0 : t1, o01 = (q & 1) ? t1 : t0;
                const float s23 = (q & 1) ? t2 : t3, o23 = (q & 1) ? t3 : t2;
                const float aa = o01 + DPP_GET(s01, 0xB1);
                const float bb = o23 + DPP_GET(s23, 0xB1);
                const float yv = (q & 2) ? aa : bb, ov = (q & 2) ? bb : aa;
                float s = ov + DPP_GET(yv, 0x4E);
                s += __shfl_xor(s, 4);
                sel1 = s;
            }

            // L2 per-gate partial dots: wi2.h1(k-1) + wh2.h2(k-2)
            PKMUL(p0, wi2[0],  a0l); PKFMA(p0, wi2[1],  a0h); PKFMA(p0, wi2[2],  a1l); PKFMA(p0, wi2[3],  a1h);
            PKFMA(p0, wh2[0],  b0l); PKFMA(p0, wh2[1],  b0h); PKFMA(p0, wh2[2],  b1l); PKFMA(p0, wh2[3],  b1h);
            PKMUL(p1, wi2[4],  a0l); PKFMA(p1, wi2[5],  a0h); PKFMA(p1, wi2[6],  a1l); PKFMA(p1, wi2[7],  a1h);
            PKFMA(p1, wh2[4],  b0l); PKFMA(p1, wh2[5],  b0h); PKFMA(p1, wh2[6],  b1l); PKFMA(p1, wh2[7],  b1h);
            PKMUL(p2, wi2[8],  a0l); PKFMA(p2, wi2[9],  a0h); PKFMA(p2, wi2[10], a1l); PKFMA(p2, wi2[11], a1h);
            PKFMA(p2, wh2[8],  b0l); PKFMA(p2, wh2[9],  b0h); PKFMA(p2, wh2[10], b1l); PKFMA(p2, wh2[11], b1h);
            PKMUL(p3, wi2[12], a0l); PKFMA(p3, wi2[13], a0h); PKFMA(p3, wi2[14], a1l); PKFMA(p3, wi2[15], a1h);
            PKFMA(p3, wh2[12], b0l); PKFMA(p3, wh2[13], b0h); PKFMA(p3, wh2[14], b1l); PKFMA(p3, wh2[15], b1h);
            t0 = p0.x + p0.y; t1 = p1.x + p1.y; t2 = p2.x + p2.y; t3 = p3.x + p3.y;

            float sel2;
            {
                const float s01 = (q & 1) ? t0 : t1, o01 = (q & 1) ? t1 : t0;
                const float s23 = (q & 1) ? t2 : t3, o23 = (q & 1) ? t3 : t2;
                const float aa = o01 + DPP_GET(s01, 0xB1);
                const float bb = o23 + DPP_GET(s23, 0xB1);
                const float yv = (q & 2) ? aa : bb, ov = (q & 2) ? bb : aa;
                float s = ov + DPP_GET(yv, 0x4E);
                s += __shfl_xor(s, 4);
                sel2 = s;
            }

            // L1 act + in-quad exchange + c1/h1 update (step k)
            {
                const float pre = sel1 + bb1 + wx * x;
                const float sg  = frcp(1.0f + __expf(sm * pre));
                const float act = sg + bm * (1.0f - sg);   // lane q: gate q
                const float bx  = DPP_GET(act, 0x4E);      // partner (i<->g, f<->o)
                const float p   = act * bx;                // lanes 0,2: i*g
                const float pv  = DPP_GET(p,   0x00);      // bcast i*g
                const float fv  = DPP_GET(act, 0x55);      // bcast f
                c1[n] = fv * c1[n] + pv;
                const float th = 1.0f - 2.0f * frcp(__expf(2.0f * c1[n]) + 1.0f);
                if (ul && c == 3) h1buf[n][wb][a] = act * th;   // q==3: act = o
            }

            // L2 act + exchange + c2/h2 update (step k-1; masked at k=0)
            {
                const float pre = sel2 + bb2;
                const float sg  = frcp(1.0f + __expf(sm * pre));
                const float act = sg + bm * (1.0f - sg);
                const float bx  = DPP_GET(act, 0x4E);
                const float p   = act * bx;
                const float pv  = DPP_GET(p,   0x00);
                const float fv  = DPP_GET(act, 0x55);
                c2[n] = fv * c2[n] + km * pv;              // k=0: c2 stays 0
                const float th = 1.0f - 2.0f * frcp(__expf(2.0f * c2[n]) + 1.0f);
                if (ul && c == 3) h2buf[n][wb][a] = act * th;   // k=0 writes 0
            }
        }

        __syncthreads();                                   // the one barrier
    }

    // epilogue: y(T-1) from h2buf[yb][TLEN & 1] (written at iter k=TLEN)
    if (ylane) {
        const f4 hv = *(const f4*)&h2buf[yb][TLEN & 1][sjj * 4];
        const f4 wl = *(const f4*)&sh_wl[sjj * 4];
        float yp = hv.x*wl.x + hv.y*wl.y + hv.z*wl.z + hv.w*wl.w;
        yp = DPP_XADD(yp, 0xB1);  yp = DPP_XADD(yp, 0x4E);
        yp += __shfl_xor(yp, 4);  yp += __shfl_xor(yp, 8);
        if (sjj == 0) out[(size_t)(b0 + yb) * TLEN + (TLEN - 1)] = yp + blin;
    }
}

extern "C" void kernel_launch(void* const* d_in, const int* in_sizes, int n_in,
                              void* d_out, int out_size, void* d_ws, size_t ws_size,
                              hipStream_t stream)
{
    const float* input = (const float*)d_in[0];
    const float* W_ih1 = (const float*)d_in[1];
    const float* W_hh1 = (const float*)d_in[2];
    const float* b_ih1 = (const float*)d_in[3];
    const float* b_hh1 = (const float*)d_in[4];
    const float* W_ih2 = (const float*)d_in[5];
    const float* W_hh2 = (const float*)d_in[6];
    const float* b_ih2 = (const float*)d_in[7];
    const float* b_hh2 = (const float*)d_in[8];
    const float* W_lin = (const float*)d_in[9];
    const float* b_lin = (const float*)d_in[10];

    float* out = (float*)d_out;

    hipLaunchKernelGGL(lstm2_kernel, dim3(NBLK), dim3(NTHR), 0, stream,
                       input, W_ih1, W_hh1, b_ih1, b_hh1,
                       W_ih2, W_hh2, b_ih2, b_hh2, W_lin, b_lin,
                       out);
}